// Round 8
// baseline (163.089 us; speedup 1.0000x reference)
//
#include <hip/hip_runtime.h>

// CTR-GC: N=64, C_IN=C_OUT=128, T=128, V=25, REL=16. fp32 in/out, bf16 MFMA inside.
// k_prep: 2048 single-shot blocks; loads 32c x 400j tile (swizzled LDS), writes
//         per-tb mean partials to xmp, emits bf16 B-frags to Xf (cvt_pk packed).
// k_adj : sums xmp partials -> xms; adjacency in LDS (bf16 B-frag order);
//         also emits W3 in bf16 A-frag order (n==0 blocks).
// k_main: NO GEMM1 staging: B-frags read directly from Xf (frag-ordered, L2/L3),
//         A-frags from W3f -> no pre-C barriers, waves free-run. LDS = 66,560 B
//         C/D scratch only; launch_bounds(1024,8) -> 64-reg cap, 2 blocks/CU.
//         XCD-aware block remap: all 8 tb of one n on one XCD (adjT L2-resident).

#define NB   64
#define CIN  128
#define COUT 128
#define TT   128
#define VV   25
#define REL  16

#define JT 25                       // j-tiles (j = t_local*25+v, 400 = 25*16)
#define KT 4                        // k-tiles of 32
#define XF_BYTES (JT * KT * 1024)   // 102,400 per (n,tb) block
#define X3_STRIDE 1040              // x3 row stride (65*16B, de-banked)
#define LDS_BYTES (64 * X3_STRIDE)  // 66,560 C/D scratch
#define TSTRIDE 416                 // k_prep tile row stride (416 % 32 == 0)
#define XMP_PLANE (NB * CIN * VV)   // 204,800 floats per tb-plane

typedef __attribute__((ext_vector_type(8))) short bf16x8;
typedef __attribute__((ext_vector_type(4))) float f32x4;

__device__ inline short f2bf(float f) {   // RNE f32->bf16 (finite inputs)
    unsigned u = __float_as_uint(f);
    u += 0x7fff + ((u >> 16) & 1);
    return (short)(u >> 16);
}

__device__ inline unsigned cvtpk(float lo, float hi) {  // 2xf32 -> packed bf16 (RNE)
    unsigned r;
    asm("v_cvt_pk_bf16_f32 %0, %1, %2" : "=v"(r) : "v"(lo), "v"(hi));
    return r;
}

// ---------------- K1: x -> (mean partials to xmp, bf16 frag Xf) ----------------
// grid (32, 64): blockIdx.x = kt*8 + tb. 256 thr. Single tile, one barrier.
__launch_bounds__(256)
__global__ void k_prep(const float* __restrict__ x, float* __restrict__ xmp,
                       char* __restrict__ Xf) {
    __shared__ float tile[32 * TSTRIDE];   // 53,248 B
    int tid = threadIdx.x;
    int kt = blockIdx.x >> 3, tb = blockIdx.x & 7, n = blockIdx.y;
    int c0 = kt * 32;

    // load 32 rows x 400 floats, swizzled: j' = j ^ (((c>>3)&1)<<4)
    const float* src = x + (size_t)(n * CIN + c0) * 3200 + tb * 400;
#pragma unroll
    for (int p = 0; p < 13; ++p) {
        int i = tid + p * 256;
        if (i < 3200) {
            int c = i / 100, q = i - c * 100;
            int sw = ((c >> 3) & 1) << 4;
            *reinterpret_cast<float4*>(&tile[c * TSTRIDE + ((q * 4) ^ sw)]) =
                *reinterpret_cast<const float4*>(src + (size_t)c * 3200 + q * 4);
        }
    }
    __syncthreads();

    // mean partials over this block's 16 t -> plain store into xmp[tb] plane
#pragma unroll
    for (int pp = 0; pp < 4; ++pp) {
        int p = tid + pp * 256;
        if (p < 800) {
            int c = p / 25, v = p - c * 25;
            int sw = ((c >> 3) & 1) << 4;
            float s = 0.f;
#pragma unroll
            for (int t = 0; t < 16; ++t) s += tile[c * TSTRIDE + ((t * 25 + v) ^ sw)];
            xmp[(size_t)tb * XMP_PLANE + ((size_t)n * CIN + c0 + c) * VV + v] = s;
        }
    }

    // emit bf16 frags: 1600 chunks of 16 B (cvt_pk packs; 2-way LDS reads)
    char* dst = Xf + (size_t)(n * 8 + tb) * XF_BYTES + (size_t)kt * 25600;
    for (int ch = tid; ch < 1600; ch += 256) {
        int l = ch & 63, jt = ch >> 6;
        int j = jt * 16 + (l & 15);
        int cl = 8 * (l >> 4);
        int sw = ((l >> 4) & 1) << 4;   // rows cl..cl+7: (row>>3)&1 == (l>>4)&1
        float f[8];
#pragma unroll
        for (int b = 0; b < 8; ++b) f[b] = tile[(cl + b) * TSTRIDE + (j ^ sw)];
        uint4 vv;
        vv.x = cvtpk(f[0], f[1]); vv.y = cvtpk(f[2], f[3]);
        vv.z = cvtpk(f[4], f[5]); vv.w = cvtpk(f[6], f[7]);
        *reinterpret_cast<uint4*>(dst + (size_t)ch * 16) = vv;
    }
}

// ---------------- K2: adjacency -> bf16 B-fragment order (LDS-staged) ----------------
// grid (N, 4): n, o-chunk of 32. adjT region per (n,o): 2048 B.
// The 4 blocks with n==0 additionally emit W3 in bf16 A-frag order to W3f (32 KB).
__global__ void k_adj(const float* __restrict__ xmp,
                      const float* __restrict__ A, const float* __restrict__ alphap,
                      const float* __restrict__ W1, const float* __restrict__ b1,
                      const float* __restrict__ W2, const float* __restrict__ b2,
                      const float* __restrict__ W4, const float* __restrict__ b4,
                      const float* __restrict__ W3, char* __restrict__ W3f,
                      char* __restrict__ adjT) {
    __shared__ char adjS[32 * 2048];   // 64 KB staging
    __shared__ float xms[CIN * VV];
    __shared__ float W1s[REL * CIN];
    __shared__ float W2s[REL * CIN];
    __shared__ float x1s[REL * VV];
    __shared__ float x2s[REL * VV];
    __shared__ float W4s[32 * REL];
    __shared__ float b4s[32];

    int tid = threadIdx.x;
    int n = blockIdx.x;
    int o0 = blockIdx.y * 32;

    // W3 -> frag order, once (n==0 blocks; 4 blocks x 512 chunks = 2048 chunks)
    if (n == 0) {
#pragma unroll
        for (int pass = 0; pass < 2; ++pass) {
            int chunk = blockIdx.y * 512 + pass * 256 + tid;
            int l = chunk & 63;
            int frag = chunk >> 6;                 // ct*4 + kt
            int ct = frag >> 2, kt = frag & 3;
            int c = ct * 16 + (l & 15);
            int kb = kt * 32 + 8 * (l >> 4);
            const float4 f0 = *reinterpret_cast<const float4*>(&W3[(size_t)c * CIN + kb]);
            const float4 f1 = *reinterpret_cast<const float4*>(&W3[(size_t)c * CIN + kb + 4]);
            uint4 vv;
            vv.x = cvtpk(f0.x, f0.y); vv.y = cvtpk(f0.z, f0.w);
            vv.z = cvtpk(f1.x, f1.y); vv.w = cvtpk(f1.z, f1.w);
            *reinterpret_cast<uint4*>(W3f + (size_t)chunk * 16) = vv;
        }
    }

    for (int i = tid; i < 16384; i += 256) reinterpret_cast<float*>(adjS)[i] = 0.f;
    // xms = (1/T) * sum of 8 tb-partials
    for (int i = tid; i < CIN * VV; i += 256) {
        float s = 0.f;
#pragma unroll
        for (int tb = 0; tb < 8; ++tb)
            s += xmp[(size_t)tb * XMP_PLANE + (size_t)n * CIN * VV + i];
        xms[i] = s * (1.0f / TT);
    }
    for (int i = tid; i < REL * CIN; i += 256) { W1s[i] = W1[i]; W2s[i] = W2[i]; }
    for (int i = tid; i < 32 * REL; i += 256) W4s[i] = W4[o0 * REL + i];
    if (tid < 32) b4s[tid] = b4[o0 + tid];
    __syncthreads();

    for (int task = tid; task < 2 * REL * VV; task += 256) {
        int rv = task % (REL * VV);
        int which = task / (REL * VV);
        int r = rv / VV, v = rv % VV;
        const float* Ws = which ? W2s : W1s;
        float s = 0.f;
#pragma unroll 8
        for (int c = 0; c < CIN; ++c) s = fmaf(Ws[r * CIN + c], xms[c * VV + v], s);
        s += which ? b2[r] : b1[r];
        (which ? x2s : x1s)[rv] = s;
    }
    __syncthreads();

    float alpha = alphap[0];
    for (int p = tid; p < VV * VV; p += 256) {
        int v = p / VV, u = p % VV;
        float d[REL];
#pragma unroll
        for (int r = 0; r < REL; ++r) d[r] = tanhf(x1s[r * VV + v] - x2s[r * VV + u]);
        float Avu = A[v * VV + u];
        // B-frag offset: b_frag[b] = adj[v = 8*(l>>4)+b][u = ut*16 + (l&15)]
        int off = (u >> 4) * 1024 + (((u & 15) + 16 * (v >> 3)) * 16) + (v & 7) * 2;
        for (int oo = 0; oo < 32; ++oo) {
            float s = 0.f;
#pragma unroll
            for (int r = 0; r < REL; ++r) s = fmaf(W4s[oo * REL + r], d[r], s);
            float val = alpha * (s + b4s[oo]) + Avu;
            *(short*)(adjS + oo * 2048 + off) = f2bf(val);
        }
    }
    __syncthreads();

    float4* dst = reinterpret_cast<float4*>(adjT + (size_t)(n * COUT + o0) * 2048);
    const float4* src = reinterpret_cast<const float4*>(adjS);
    for (int i = tid; i < 4096; i += 256) dst[i] = src[i];
}

// ---------------- K3: two fused MFMA GEMMs (global-direct GEMM1, 2 blk/CU) -------
// grid 512 flat, XCD-remapped: id=(q<<3)|r -> n = r*8 + (q>>3), tb = q&7.
// Wave w: ct = w>>1, j-half = w&1. acc[13] = 52 regs.
__launch_bounds__(1024, 8)
__global__ void k_main(const char* __restrict__ Xf, const char* __restrict__ W3f,
                       const float* __restrict__ b3, const char* __restrict__ adjT,
                       float* __restrict__ out) {
    __shared__ __align__(16) char lds[LDS_BYTES];   // 66,560 B

    int tid = threadIdx.x;
    int id = blockIdx.x;
    int q = id >> 3, r8 = id & 7;
    int n = r8 * 8 + (q >> 3), tb = q & 7;   // same-n blocks share an XCD
    int lane = tid & 63, w = tid >> 6;
    int g = lane >> 4, lr = lane & 15;
    int ct = w >> 1, jh = w & 1;
    int jt0 = jh ? 13 : 0;
    int njt = jh ? 12 : 13;

    const char* xfb = Xf + (size_t)(n * 8 + tb) * XF_BYTES;

    // ---- GEMM1: x3 = W3 @ X, operands straight from global (no LDS, no barriers) ----
    f32x4 acc[13];
#pragma unroll
    for (int u = 0; u < 13; ++u) acc[u] = f32x4{0.f, 0.f, 0.f, 0.f};
#pragma unroll
    for (int kt = 0; kt < KT; ++kt) {
        bf16x8 a = *reinterpret_cast<const bf16x8*>(
            W3f + (size_t)((ct * 4 + kt) * 64 + lane) * 16);
#pragma unroll
        for (int u = 0; u < 13; ++u) {
            if (u < njt) {
                int jt = jt0 + u;
                bf16x8 bx = *reinterpret_cast<const bf16x8*>(
                    xfb + (size_t)((kt * JT + jt) * 64 + lane) * 16);
                acc[u] = __builtin_amdgcn_mfma_f32_16x16x32_bf16(a, bx, acc[u], 0, 0, 0);
            }
        }
    }

    // ---- zero v = 25..31 pad slots of all 64 scratch rows (C never writes pads) ----
#pragma unroll
    for (int z = 0; z < 7; ++z) {
        int idx = tid + z * 1024;
        if (idx < 7168) {
            int c = idx / 112;
            int rem = idx - c * 112;
            int t = rem / 7, qq = rem - t * 7;
            *(short*)(lds + (size_t)c * X3_STRIDE + (t + 48) * 16 + 2 + qq * 2) = 0;
        }
    }

    float bv[4];
#pragma unroll
    for (int r = 0; r < 4; ++r) bv[r] = b3[ct * 16 + 4 * g + r];

    const char* adjTb = adjT + (size_t)(n * COUT) * 2048;
    int t0 = tb * 16;

    // ---- Phase C/D: two c-halves of 64 rows ----
#pragma unroll
    for (int hh = 0; hh < 2; ++hh) {
        // C: waves owning this half write their 16 rows (A-frag order, j-half each)
        if ((ct >> 2) == hh) {
            int cb = (ct & 3) * 16 + 4 * g;
#pragma unroll
            for (int u = 0; u < 13; ++u) {
                if (u < njt) {
                    int j = (jt0 + u) * 16 + lr;
                    int t = j / 25, v = j - t * 25;
                    int off = (t + 16 * (v >> 3)) * 16 + (v & 7) * 2;
#pragma unroll
                    for (int r = 0; r < 4; ++r)
                        *(short*)(lds + (size_t)(cb + r) * X3_STRIDE + off) =
                            f2bf(acc[u][r] + bv[r]);
                }
            }
        }
        __syncthreads();   // half's rows (and pads) visible to all waves

        // D: 4 rows per wave
#pragma unroll
        for (int i = 0; i < 4; ++i) {
            int cl = w * 4 + i;
            int c = hh * 64 + cl;
            bf16x8 a = *reinterpret_cast<const bf16x8*>(
                lds + (size_t)cl * X3_STRIDE + lane * 16);
            const bf16x8* bp = reinterpret_cast<const bf16x8*>(adjTb + (size_t)c * 2048);
            bf16x8 b0 = bp[lane];
            bf16x8 b1 = bp[64 + lane];
            f32x4 z = {0.f, 0.f, 0.f, 0.f};
            f32x4 d0 = __builtin_amdgcn_mfma_f32_16x16x32_bf16(a, b0, z, 0, 0, 0);
            f32x4 d1 = __builtin_amdgcn_mfma_f32_16x16x32_bf16(a, b1, z, 0, 0, 0);
            float* ob = out + ((size_t)(n * COUT + c) * TT + t0) * VV;
#pragma unroll
            for (int rr = 0; rr < 4; ++rr) {
                int t = 4 * g + rr;
                ob[(size_t)t * VV + lr] = d0[rr];
                if (lr < 9) ob[(size_t)t * VV + 16 + lr] = d1[rr];
            }
        }
        __syncthreads();   // D reads done before next half's C overwrites
    }
}

extern "C" void kernel_launch(void* const* d_in, const int* in_sizes, int n_in,
                              void* d_out, int out_size, void* d_ws, size_t ws_size,
                              hipStream_t stream) {
    const float* x     = (const float*)d_in[0];
    const float* A     = (const float*)d_in[1];
    const float* alpha = (const float*)d_in[2];
    const float* W1    = (const float*)d_in[3];
    const float* b1    = (const float*)d_in[4];
    const float* W2    = (const float*)d_in[5];
    const float* b2    = (const float*)d_in[6];
    const float* W3    = (const float*)d_in[7];
    const float* b3    = (const float*)d_in[8];
    const float* W4    = (const float*)d_in[9];
    const float* b4    = (const float*)d_in[10];
    float* out = (float*)d_out;

    float* xmp = (float*)d_ws;                                // 6,553,600 B
    char* adjT = (char*)d_ws + 6553600;                       // 16,777,216 B
    char* W3f  = (char*)d_ws + 6553600 + 16777216;            // 32,768 B
    char* Xf   = (char*)d_ws + 6553600 + 16777216 + 32768;    // 52,428,800 B

    k_prep<<<dim3(32, NB), 256, 0, stream>>>(x, xmp, Xf);
    k_adj<<<dim3(NB, 4), 256, 0, stream>>>(xmp, A, alpha, W1, b1, W2, b2, W4, b4,
                                           W3, W3f, adjT);
    k_main<<<dim3(512), 1024, 0, stream>>>(Xf, W3f, b3, adjT, out);
}

// Round 9
// 117.470 us; speedup vs baseline: 1.3883x; 1.3883x over previous
//
#include <hip/hip_runtime.h>

// CTR-GC: N=64, C_IN=C_OUT=128, T=128, V=25, REL=16. fp32 in/out, bf16 MFMA inside.
// k_prep: 2048 tile-blocks, 512 thr (2 blk/CU): loads 32c x 400j tile (swizzled),
//         writes per-tb mean partials to xmp, emits bf16 B-frags to Xf (cvt_pk).
// k_adj : sums xmp partials -> xms; adjacency in LDS (bf16 B-frag order);
//         also emits W3 in bf16 A-frag order (n==0 blocks).
// k_main: global-direct GEMM1 (Xf/W3f frag reads from L2/L3, no staging barriers,
//         waves free-run -> co-resident blocks skew phases). LDS = 66,560 C/D
//         scratch. Default 1024-thread bound (NO min-waves clause: R8's (1024,8)
//         split the unified reg file 32+32 and spilled acc[13]=52).
//         XCD remap: all 8 tb of one n share an XCD (adjT L2-resident).

#define NB   64
#define CIN  128
#define COUT 128
#define TT   128
#define VV   25
#define REL  16

#define JT 25                       // j-tiles (j = t_local*25+v, 400 = 25*16)
#define KT 4                        // k-tiles of 32
#define XF_BYTES (JT * KT * 1024)   // 102,400 per (n,tb) block
#define X3_STRIDE 1040              // x3 row stride (65*16B, de-banked)
#define LDS_BYTES (64 * X3_STRIDE)  // 66,560 C/D scratch
#define TSTRIDE 416                 // k_prep tile row stride (416 % 32 == 0)
#define XMP_PLANE (NB * CIN * VV)   // 204,800 floats per tb-plane

typedef __attribute__((ext_vector_type(8))) short bf16x8;
typedef __attribute__((ext_vector_type(4))) float f32x4;

__device__ inline short f2bf(float f) {   // RNE f32->bf16 (finite inputs)
    unsigned u = __float_as_uint(f);
    u += 0x7fff + ((u >> 16) & 1);
    return (short)(u >> 16);
}

__device__ inline unsigned cvtpk(float lo, float hi) {  // 2xf32 -> packed bf16 (RNE)
    unsigned r;
    asm("v_cvt_pk_bf16_f32 %0, %1, %2" : "=v"(r) : "v"(lo), "v"(hi));
    return r;
}

// ---------------- K1: x -> (mean partials to xmp, bf16 frag Xf) ----------------
// grid (32, 64): blockIdx.x = kt*8 + tb. 512 thr, 2 blk/CU. One barrier.
__launch_bounds__(512)
__global__ void k_prep(const float* __restrict__ x, float* __restrict__ xmp,
                       char* __restrict__ Xf) {
    __shared__ float tile[32 * TSTRIDE];   // 53,248 B
    int tid = threadIdx.x;
    int kt = blockIdx.x >> 3, tb = blockIdx.x & 7, n = blockIdx.y;
    int c0 = kt * 32;

    // load 32 rows x 400 floats, swizzled: j' = j ^ (((c>>3)&1)<<4)
    const float* src = x + (size_t)(n * CIN + c0) * 3200 + tb * 400;
#pragma unroll
    for (int p = 0; p < 7; ++p) {
        int i = tid + p * 512;
        if (i < 3200) {
            int c = i / 100, q = i - c * 100;
            int sw = ((c >> 3) & 1) << 4;
            *reinterpret_cast<float4*>(&tile[c * TSTRIDE + ((q * 4) ^ sw)]) =
                *reinterpret_cast<const float4*>(src + (size_t)c * 3200 + q * 4);
        }
    }
    __syncthreads();

    // mean partials over this block's 16 t -> plain store into xmp[tb] plane
#pragma unroll
    for (int pp = 0; pp < 2; ++pp) {
        int p = tid + pp * 512;
        if (p < 800) {
            int c = p / 25, v = p - c * 25;
            int sw = ((c >> 3) & 1) << 4;
            float s = 0.f;
#pragma unroll
            for (int t = 0; t < 16; ++t) s += tile[c * TSTRIDE + ((t * 25 + v) ^ sw)];
            xmp[(size_t)tb * XMP_PLANE + ((size_t)n * CIN + c0 + c) * VV + v] = s;
        }
    }

    // emit bf16 frags: 1600 chunks of 16 B (cvt_pk packs; 2-way LDS reads)
    char* dst = Xf + (size_t)(n * 8 + tb) * XF_BYTES + (size_t)kt * 25600;
#pragma unroll
    for (int p = 0; p < 4; ++p) {
        int ch = tid + p * 512;
        if (ch < 1600) {
            int l = ch & 63, jt = ch >> 6;
            int j = jt * 16 + (l & 15);
            int cl = 8 * (l >> 4);
            int sw = ((l >> 4) & 1) << 4;   // rows cl..cl+7: (row>>3)&1 == (l>>4)&1
            float f[8];
#pragma unroll
            for (int b = 0; b < 8; ++b) f[b] = tile[(cl + b) * TSTRIDE + (j ^ sw)];
            uint4 vv;
            vv.x = cvtpk(f[0], f[1]); vv.y = cvtpk(f[2], f[3]);
            vv.z = cvtpk(f[4], f[5]); vv.w = cvtpk(f[6], f[7]);
            *reinterpret_cast<uint4*>(dst + (size_t)ch * 16) = vv;
        }
    }
}

// ---------------- K2: adjacency -> bf16 B-fragment order (LDS-staged) ----------------
// grid (N, 4): n, o-chunk of 32. adjT region per (n,o): 2048 B.
// The 4 blocks with n==0 additionally emit W3 in bf16 A-frag order to W3f (32 KB).
__global__ void k_adj(const float* __restrict__ xmp,
                      const float* __restrict__ A, const float* __restrict__ alphap,
                      const float* __restrict__ W1, const float* __restrict__ b1,
                      const float* __restrict__ W2, const float* __restrict__ b2,
                      const float* __restrict__ W4, const float* __restrict__ b4,
                      const float* __restrict__ W3, char* __restrict__ W3f,
                      char* __restrict__ adjT) {
    __shared__ char adjS[32 * 2048];   // 64 KB staging
    __shared__ float xms[CIN * VV];
    __shared__ float W1s[REL * CIN];
    __shared__ float W2s[REL * CIN];
    __shared__ float x1s[REL * VV];
    __shared__ float x2s[REL * VV];
    __shared__ float W4s[32 * REL];
    __shared__ float b4s[32];

    int tid = threadIdx.x;
    int n = blockIdx.x;
    int o0 = blockIdx.y * 32;

    // W3 -> frag order, once (n==0 blocks; 4 blocks x 512 chunks = 2048 chunks)
    if (n == 0) {
#pragma unroll
        for (int pass = 0; pass < 2; ++pass) {
            int chunk = blockIdx.y * 512 + pass * 256 + tid;
            int l = chunk & 63;
            int frag = chunk >> 6;                 // ct*4 + kt
            int ct = frag >> 2, kt = frag & 3;
            int c = ct * 16 + (l & 15);
            int kb = kt * 32 + 8 * (l >> 4);
            const float4 f0 = *reinterpret_cast<const float4*>(&W3[(size_t)c * CIN + kb]);
            const float4 f1 = *reinterpret_cast<const float4*>(&W3[(size_t)c * CIN + kb + 4]);
            uint4 vv;
            vv.x = cvtpk(f0.x, f0.y); vv.y = cvtpk(f0.z, f0.w);
            vv.z = cvtpk(f1.x, f1.y); vv.w = cvtpk(f1.z, f1.w);
            *reinterpret_cast<uint4*>(W3f + (size_t)chunk * 16) = vv;
        }
    }

    for (int i = tid; i < 16384; i += 256) reinterpret_cast<float*>(adjS)[i] = 0.f;
    // xms = (1/T) * sum of 8 tb-partials
    for (int i = tid; i < CIN * VV; i += 256) {
        float s = 0.f;
#pragma unroll
        for (int tb = 0; tb < 8; ++tb)
            s += xmp[(size_t)tb * XMP_PLANE + (size_t)n * CIN * VV + i];
        xms[i] = s * (1.0f / TT);
    }
    for (int i = tid; i < REL * CIN; i += 256) { W1s[i] = W1[i]; W2s[i] = W2[i]; }
    for (int i = tid; i < 32 * REL; i += 256) W4s[i] = W4[o0 * REL + i];
    if (tid < 32) b4s[tid] = b4[o0 + tid];
    __syncthreads();

    for (int task = tid; task < 2 * REL * VV; task += 256) {
        int rv = task % (REL * VV);
        int which = task / (REL * VV);
        int r = rv / VV, v = rv % VV;
        const float* Ws = which ? W2s : W1s;
        float s = 0.f;
#pragma unroll 8
        for (int c = 0; c < CIN; ++c) s = fmaf(Ws[r * CIN + c], xms[c * VV + v], s);
        s += which ? b2[r] : b1[r];
        (which ? x2s : x1s)[rv] = s;
    }
    __syncthreads();

    float alpha = alphap[0];
    for (int p = tid; p < VV * VV; p += 256) {
        int v = p / VV, u = p % VV;
        float d[REL];
#pragma unroll
        for (int r = 0; r < REL; ++r) d[r] = tanhf(x1s[r * VV + v] - x2s[r * VV + u]);
        float Avu = A[v * VV + u];
        // B-frag offset: b_frag[b] = adj[v = 8*(l>>4)+b][u = ut*16 + (l&15)]
        int off = (u >> 4) * 1024 + (((u & 15) + 16 * (v >> 3)) * 16) + (v & 7) * 2;
        for (int oo = 0; oo < 32; ++oo) {
            float s = 0.f;
#pragma unroll
            for (int r = 0; r < REL; ++r) s = fmaf(W4s[oo * REL + r], d[r], s);
            float val = alpha * (s + b4s[oo]) + Avu;
            *(short*)(adjS + oo * 2048 + off) = f2bf(val);
        }
    }
    __syncthreads();

    float4* dst = reinterpret_cast<float4*>(adjT + (size_t)(n * COUT + o0) * 2048);
    const float4* src = reinterpret_cast<const float4*>(adjS);
    for (int i = tid; i < 4096; i += 256) dst[i] = src[i];
}

// ---------------- K3: two fused MFMA GEMMs (global-direct GEMM1, free-run) -------
// grid 512 flat, XCD-remapped: id=(q<<3)|r -> n = r*8 + (q>>3), tb = q&7.
// Wave w: ct = w>>1, j-half = w&1. acc[13] = 52 regs. Default bound: no reg cap
// beyond the natural 1024-thread limit (R6/R7 compiled this to 52 VGPR).
__launch_bounds__(1024)
__global__ void k_main(const char* __restrict__ Xf, const char* __restrict__ W3f,
                       const float* __restrict__ b3, const char* __restrict__ adjT,
                       float* __restrict__ out) {
    __shared__ __align__(16) char lds[LDS_BYTES];   // 66,560 B

    int tid = threadIdx.x;
    int id = blockIdx.x;
    int q = id >> 3, r8 = id & 7;
    int n = r8 * 8 + (q >> 3), tb = q & 7;   // same-n blocks share an XCD
    int lane = tid & 63, w = tid >> 6;
    int g = lane >> 4, lr = lane & 15;
    int ct = w >> 1, jh = w & 1;
    int jt0 = jh ? 13 : 0;
    int njt = jh ? 12 : 13;

    const char* xfb = Xf + (size_t)(n * 8 + tb) * XF_BYTES;

    // ---- GEMM1: x3 = W3 @ X, operands straight from global (no LDS, no barriers) ----
    f32x4 acc[13];
#pragma unroll
    for (int u = 0; u < 13; ++u) acc[u] = f32x4{0.f, 0.f, 0.f, 0.f};
#pragma unroll
    for (int kt = 0; kt < KT; ++kt) {
        bf16x8 a = *reinterpret_cast<const bf16x8*>(
            W3f + (size_t)((ct * 4 + kt) * 64 + lane) * 16);
#pragma unroll
        for (int u = 0; u < 13; ++u) {
            if (u < njt) {
                int jt = jt0 + u;
                bf16x8 bx = *reinterpret_cast<const bf16x8*>(
                    xfb + (size_t)((kt * JT + jt) * 64 + lane) * 16);
                acc[u] = __builtin_amdgcn_mfma_f32_16x16x32_bf16(a, bx, acc[u], 0, 0, 0);
            }
        }
    }

    // ---- zero v = 25..31 pad slots of all 64 scratch rows (C never writes pads) ----
#pragma unroll
    for (int z = 0; z < 7; ++z) {
        int idx = tid + z * 1024;
        if (idx < 7168) {
            int c = idx / 112;
            int rem = idx - c * 112;
            int t = rem / 7, qq = rem - t * 7;
            *(short*)(lds + (size_t)c * X3_STRIDE + (t + 48) * 16 + 2 + qq * 2) = 0;
        }
    }

    float bv[4];
#pragma unroll
    for (int r = 0; r < 4; ++r) bv[r] = b3[ct * 16 + 4 * g + r];

    const char* adjTb = adjT + (size_t)(n * COUT) * 2048;
    int t0 = tb * 16;

    // ---- Phase C/D: two c-halves of 64 rows ----
#pragma unroll
    for (int hh = 0; hh < 2; ++hh) {
        // C: waves owning this half write their 16 rows (A-frag order, j-half each)
        if ((ct >> 2) == hh) {
            int cb = (ct & 3) * 16 + 4 * g;
#pragma unroll
            for (int u = 0; u < 13; ++u) {
                if (u < njt) {
                    int j = (jt0 + u) * 16 + lr;
                    int t = j / 25, v = j - t * 25;
                    int off = (t + 16 * (v >> 3)) * 16 + (v & 7) * 2;
#pragma unroll
                    for (int r = 0; r < 4; ++r)
                        *(short*)(lds + (size_t)(cb + r) * X3_STRIDE + off) =
                            f2bf(acc[u][r] + bv[r]);
                }
            }
        }
        __syncthreads();   // half's rows (and pads) visible to all waves

        // D: 4 rows per wave
#pragma unroll
        for (int i = 0; i < 4; ++i) {
            int cl = w * 4 + i;
            int c = hh * 64 + cl;
            bf16x8 a = *reinterpret_cast<const bf16x8*>(
                lds + (size_t)cl * X3_STRIDE + lane * 16);
            const bf16x8* bp = reinterpret_cast<const bf16x8*>(adjTb + (size_t)c * 2048);
            bf16x8 b0 = bp[lane];
            bf16x8 b1 = bp[64 + lane];
            f32x4 z = {0.f, 0.f, 0.f, 0.f};
            f32x4 d0 = __builtin_amdgcn_mfma_f32_16x16x32_bf16(a, b0, z, 0, 0, 0);
            f32x4 d1 = __builtin_amdgcn_mfma_f32_16x16x32_bf16(a, b1, z, 0, 0, 0);
            float* ob = out + ((size_t)(n * COUT + c) * TT + t0) * VV;
#pragma unroll
            for (int rr = 0; rr < 4; ++rr) {
                int t = 4 * g + rr;
                ob[(size_t)t * VV + lr] = d0[rr];
                if (lr < 9) ob[(size_t)t * VV + 16 + lr] = d1[rr];
            }
        }
        __syncthreads();   // D reads done before next half's C overwrites
    }
}

extern "C" void kernel_launch(void* const* d_in, const int* in_sizes, int n_in,
                              void* d_out, int out_size, void* d_ws, size_t ws_size,
                              hipStream_t stream) {
    const float* x     = (const float*)d_in[0];
    const float* A     = (const float*)d_in[1];
    const float* alpha = (const float*)d_in[2];
    const float* W1    = (const float*)d_in[3];
    const float* b1    = (const float*)d_in[4];
    const float* W2    = (const float*)d_in[5];
    const float* b2    = (const float*)d_in[6];
    const float* W3    = (const float*)d_in[7];
    const float* b3    = (const float*)d_in[8];
    const float* W4    = (const float*)d_in[9];
    const float* b4    = (const float*)d_in[10];
    float* out = (float*)d_out;

    float* xmp = (float*)d_ws;                                // 6,553,600 B
    char* adjT = (char*)d_ws + 6553600;                       // 16,777,216 B
    char* W3f  = (char*)d_ws + 6553600 + 16777216;            // 32,768 B
    char* Xf   = (char*)d_ws + 6553600 + 16777216 + 32768;    // 52,428,800 B

    k_prep<<<dim3(32, NB), 512, 0, stream>>>(x, xmp, Xf);
    k_adj<<<dim3(NB, 4), 256, 0, stream>>>(xmp, A, alpha, W1, b1, W2, b2, W4, b4,
                                           W3, W3f, adjT);
    k_main<<<dim3(512), 1024, 0, stream>>>(Xf, W3f, b3, adjT, out);
}